// Round 16
// baseline (270.493 us; speedup 1.0000x reference)
//
#include <hip/hip_runtime.h>
#include <math.h>

#define HW   4096
#define CDIM 256

typedef float f32x4  __attribute__((ext_vector_type(4)));
typedef float f32x2  __attribute__((ext_vector_type(2)));
typedef short short8 __attribute__((ext_vector_type(8)));

// d_out layout (float offsets)
#define FUSED_SZ (4ULL*256*HW)
#define OFF_SZ   (4ULL*72*HW)

static __device__ __forceinline__ unsigned short f2b(float f) {
    unsigned u = __float_as_uint(f);
    unsigned r = (u + 0x7fffu + ((u >> 16) & 1u)) >> 16;
    return (unsigned short)r;
}
static __device__ __forceinline__ float b2f(short h) {
    return __uint_as_float(((unsigned)(unsigned short)h) << 16);
}
// packed f32x2 -> bf16x2 (lo = a, hi = b), RNE in HW
static __device__ __forceinline__ unsigned pk_bf16(float a, float b) {
    unsigned r;
    asm("v_cvt_pk_bf16_f32 %0, %1, %2" : "=v"(r) : "v"(a), "v"(b));
    return r;
}
union U8 { unsigned u[4]; short8 s; };

// fp8x2 -> f32x2 unpack; word-select must be a LITERAL (builtin constraint)
#define CVT8(a, HI) ((f32x2)__builtin_amdgcn_cvt_pk_f32_fp8((int)(a), HI))

// ---------------------------------------------------------------------------
// Kernel 0: fused one-time weight preps (3 ranges in one launch).
// ---------------------------------------------------------------------------
__global__ __launch_bounds__(256) void prep_all(
    const float* __restrict__ w_off, const float* __restrict__ dcn_w,
    const float* __restrict__ wq, const float* __restrict__ wk,
    const float* __restrict__ wv,
    unsigned short* __restrict__ wT2, unsigned short* __restrict__ dcnwT,
    unsigned short* __restrict__ wqkvT)
{
    const int bid = blockIdx.x;
    if (bid < 2304) {
        int idx = bid * 256 + threadIdx.x;
        int kk  = idx / (128 * 512);
        int rem = idx - kk * 128 * 512;
        int o = rem >> 9;
        int c = rem & 511;
        float v = (o < 108) ? w_off[((size_t)o * 512 + c) * 9 + kk] : 0.f;
        size_t flat = ((size_t)(kk * 16 + (c >> 5)) * 128 + o) * 32 + (c & 31);
        wT2[flat] = f2b(v);
    } else if (bid < 2880) {
        int idx = (bid - 2304) * 256 + threadIdx.x;
        if (idx < 9 * 256 * 64) {
            int k   = idx / (256 * 64);
            int rem = idx - k * 256 * 64;
            int og = rem >> 6;
            int i  = rem & 63;
            int g = og >> 6, ol = og & 63;
            size_t flat = ((size_t)((k * 4 + g) * 2 + (i >> 5)) * 64 + ol) * 32 + (i & 31);
            dcnwT[flat] = f2b(dcn_w[((size_t)og * 64 + i) * 9 + k]);
        }
    } else {
        int idx = (bid - 2880) * 256 + threadIdx.x;   // 768*256
        int o = idx >> 8;
        int c = idx & 255;
        float v = (o < 256) ? wq[(size_t)o * 256 + c]
                : (o < 512) ? wk[(size_t)(o - 256) * 256 + c]
                            : wv[(size_t)(o - 512) * 256 + c];
        wqkvT[idx] = f2b(v);
    }
}

// ---------------------------------------------------------------------------
// Kernel 0d: transpose 12 input images NCHW f32 -> NHWC bf16  xT[12][4096][256]
// ---------------------------------------------------------------------------
__global__ __launch_bounds__(256) void xprep(
    const float* __restrict__ rife, const float* __restrict__ d0,
    const float* __restrict__ d1, unsigned short* __restrict__ xT)
{
    const int pix0 = blockIdx.x * 64;
    const int img  = blockIdx.y;
    const int t    = threadIdx.x;

    const float* src = (img < 4) ? rife + (size_t)img * CDIM * HW
                     : (img < 8) ? d0 + (size_t)(img - 4) * CDIM * HW
                                 : d1 + (size_t)(img - 8) * CDIM * HW;
    unsigned short* dst = xT + (size_t)img * 4096 * 256;

    __shared__ float tile[64][65];

    for (int c0 = 0; c0 < 256; c0 += 64) {
        #pragma unroll
        for (int r = 0; r < 16; ++r) {
            int idx = t + r * 256;
            int c = idx >> 6, pp = idx & 63;
            tile[c][pp] = src[(size_t)(c0 + c) * HW + pix0 + pp];
        }
        __syncthreads();
        const int pix = t >> 2, cq = t & 3;
        const int cb = cq * 16;
        uint4 p0, p1;
        p0.x = pk_bf16(tile[cb+0][pix],  tile[cb+1][pix]);
        p0.y = pk_bf16(tile[cb+2][pix],  tile[cb+3][pix]);
        p0.z = pk_bf16(tile[cb+4][pix],  tile[cb+5][pix]);
        p0.w = pk_bf16(tile[cb+6][pix],  tile[cb+7][pix]);
        p1.x = pk_bf16(tile[cb+8][pix],  tile[cb+9][pix]);
        p1.y = pk_bf16(tile[cb+10][pix], tile[cb+11][pix]);
        p1.z = pk_bf16(tile[cb+12][pix], tile[cb+13][pix]);
        p1.w = pk_bf16(tile[cb+14][pix], tile[cb+15][pix]);
        unsigned short* p = dst + (size_t)(pix0 + pix) * 256 + c0 + cb;
        *(uint4*)p = p0;
        *(uint4*)(p + 8) = p1;
        __syncthreads();
    }
}

// ---------------------------------------------------------------------------
// Kernel 1: QKV 1x1 convs as pure-register MFMA GEMM (no LDS, no barriers).
//   Q,K -> comb_t bf16 NHWC.   V -> vbuf8 fp8-e4m3, channel-PERMUTED per
//   64-ch group: channel l = ks*32 + qq*8 + j  ->  position qq*16 + ks*8 + j.
// ---------------------------------------------------------------------------
__global__ __launch_bounds__(256) void qkv_mfma(
    const unsigned short* __restrict__ xT,
    const unsigned short* __restrict__ wqkvT,
    const float* __restrict__ bq, const float* __restrict__ bk,
    const float* __restrict__ bv,
    unsigned short* __restrict__ comb_t, unsigned char* __restrict__ vbuf8)
{
    const int pix0 = blockIdx.x * 64;
    const int type = blockIdx.y;
    const int s    = blockIdx.z;
    const int t    = threadIdx.x;
    const int wvi  = t >> 6;
    const int lane = t & 63;
    const int q    = lane >> 4;
    const int rl   = lane & 15;

    const int img = (type == 0) ? (s & 3) : (4 + s);
    const short8* X = (const short8*)(xT + (size_t)img * 4096 * 256);
    const short8* W = (const short8*)(wqkvT + (size_t)(type * 256 + wvi * 64) * 256);
    const float* bias = (type == 0) ? bq : (type == 1) ? bk : bv;

    f32x4 acc[4][4];
    #pragma unroll
    for (int mf = 0; mf < 4; ++mf)
        #pragma unroll
        for (int nf = 0; nf < 4; ++nf)
            acc[mf][nf] = (f32x4){0.f, 0.f, 0.f, 0.f};

    #pragma unroll
    for (int c8 = 0; c8 < 32; c8 += 4) {
        short8 a[4], b[4];
        #pragma unroll
        for (int mf = 0; mf < 4; ++mf)
            a[mf] = W[(size_t)(mf * 16 + rl) * 32 + c8 + q];
        #pragma unroll
        for (int nf = 0; nf < 4; ++nf)
            b[nf] = X[(size_t)(pix0 + nf * 16 + rl) * 32 + c8 + q];
        #pragma unroll
        for (int mf = 0; mf < 4; ++mf)
            #pragma unroll
            for (int nf = 0; nf < 4; ++nf)
                acc[mf][nf] = __builtin_amdgcn_mfma_f32_16x16x32_bf16(a[mf], b[nf], acc[mf][nf], 0, 0, 0);
    }

    if (type < 2) {
        unsigned short* dst = comb_t + (size_t)s * 4096 * 512 + type * 256;
        #pragma unroll
        for (int mf = 0; mf < 4; ++mf) {
            const int o_loc = wvi * 64 + mf * 16 + q * 4;
            const float4 bz = *(const float4*)(bias + o_loc);
            #pragma unroll
            for (int nf = 0; nf < 4; ++nf) {
                const int pix = pix0 + nf * 16 + rl;
                uint2 pk;
                pk.x = pk_bf16(acc[mf][nf][0] + bz.x, acc[mf][nf][1] + bz.y);
                pk.y = pk_bf16(acc[mf][nf][2] + bz.z, acc[mf][nf][3] + bz.w);
                *(uint2*)(dst + (size_t)pix * 512 + o_loc) = pk;
            }
        }
    } else {
        unsigned char* dst8 = vbuf8 + (size_t)s * 4096 * 256;
        #pragma unroll
        for (int mf = 0; mf < 4; ++mf) {
            const int l = mf * 16 + q * 4;          // local ch within 64-group
            const int p = wvi * 64 + ((l >> 3) & 3) * 16 + (l >> 5) * 8 + (l & 7);
            const float4 bz = *(const float4*)(bias + wvi * 64 + l);
            #pragma unroll
            for (int nf = 0; nf < 4; ++nf) {
                const int pix = pix0 + nf * 16 + rl;
                int u = __builtin_amdgcn_cvt_pk_fp8_f32(acc[mf][nf][0] + bz.x,
                                                        acc[mf][nf][1] + bz.y, 0, false);
                u = __builtin_amdgcn_cvt_pk_fp8_f32(acc[mf][nf][2] + bz.z,
                                                    acc[mf][nf][3] + bz.w, u, true);
                *(unsigned*)(dst8 + (size_t)pix * 256 + p) = (unsigned)u;
            }
        }
    }
}

// ---------------------------------------------------------------------------
// Kernel 2: 3x3 conv 512->108 as implicit GEMM on MFMA bf16 (r10 full-row form).
// ---------------------------------------------------------------------------
__global__ __launch_bounds__(256) void offconv_mfma(
    const unsigned short* __restrict__ comb_t,
    const unsigned short* __restrict__ wT2,
    const float* __restrict__ b_off,
    float* __restrict__ dout, float* __restrict__ mask_ws)
{
    const int bid = blockIdx.x;
    const int s = bid & 7;          // XCD = linear_bid % 8 = s
    const int h = bid >> 3;
    const int t = threadIdx.x;
    const int lane = t & 63;
    const int wid  = t >> 6;
    const int q    = lane >> 4;
    const int rl   = lane & 15;

    __shared__ __align__(16) unsigned short tb[2][792 * 8];

    const short8* cbv = (const short8*)comb_t + (size_t)s * 4096 * 64;
    const short8* wv  = (const short8*)wT2;

    const int i1 = t + 256, i2 = t + 512, i3 = t + 768;

    auto sload = [&](int idx, int c8) -> short8 {
        int x = idx >> 2, cq = idx & 3;
        int ky = x / 66, xx = x - ky * 66;
        int hh = h + ky - 1, gx = xx - 1;
        short8 v = {0, 0, 0, 0, 0, 0, 0, 0};
        if (hh >= 0 && hh < 64 && gx >= 0 && gx < 64)
            v = cbv[(size_t)(hh * 64 + gx) * 64 + c8 + cq];
        return v;
    };
    auto swrite = [&](unsigned short* buf, int idx, short8 v) {
        int x = idx >> 2, cq = idx & 3;
        int qs = cq ^ ((x >> 1) & 3);
        *((short8*)buf + x * 4 + qs) = v;
    };

    f32x4 acc[2][4];
    #pragma unroll
    for (int ma = 0; ma < 2; ++ma)
        #pragma unroll
        for (int nf = 0; nf < 4; ++nf)
            acc[ma][nf] = (f32x4){0.f, 0.f, 0.f, 0.f};

    short8 r0 = sload(t, 0), r1 = sload(i1, 0), r2 = sload(i2, 0);
    short8 r3 = {0,0,0,0,0,0,0,0};
    if (i3 < 792) r3 = sload(i3, 0);
    swrite(tb[0], t, r0); swrite(tb[0], i1, r1); swrite(tb[0], i2, r2);
    if (i3 < 792) swrite(tb[0], i3, r3);
    __syncthreads();

    for (int sl = 0; sl < 16; ++sl) {
        const int c8 = sl * 4;
        if (sl < 15) {
            r0 = sload(t, c8 + 4); r1 = sload(i1, c8 + 4); r2 = sload(i2, c8 + 4);
            if (i3 < 792) r3 = sload(i3, c8 + 4);
        }
        short8 a[2][9];
        #pragma unroll
        for (int ma = 0; ma < 2; ++ma) {
            const int o = (wid * 2 + ma) * 16 + rl;
            #pragma unroll
            for (int kk = 0; kk < 9; ++kk)
                a[ma][kk] = wv[((size_t)(kk * 16 + sl) * 128 + o) * 4 + q];
        }
        const unsigned short* bufc = tb[sl & 1];
        #pragma unroll
        for (int kk = 0; kk < 9; ++kk) {
            const int ky = kk / 3, kx = kk % 3;
            #pragma unroll
            for (int nf = 0; nf < 4; ++nf) {
                const int xr = ky * 66 + nf * 16 + rl + kx;
                short8 b = *((const short8*)bufc + xr * 4 + (q ^ ((xr >> 1) & 3)));
                acc[0][nf] = __builtin_amdgcn_mfma_f32_16x16x32_bf16(a[0][kk], b, acc[0][nf], 0, 0, 0);
                acc[1][nf] = __builtin_amdgcn_mfma_f32_16x16x32_bf16(a[1][kk], b, acc[1][nf], 0, 0, 0);
            }
        }
        if (sl < 15) {
            unsigned short* bufn = tb[(sl + 1) & 1];
            swrite(bufn, t, r0); swrite(bufn, i1, r1); swrite(bufn, i2, r2);
            if (i3 < 792) swrite(bufn, i3, r3);
        }
        __syncthreads();
    }

    const size_t obase = FUSED_SZ + (s < 4 ? 0 : OFF_SZ) + (size_t)(s & 3) * 72 * HW + (size_t)h * 64;
    const size_t mbase = (size_t)s * 36 * HW + (size_t)h * 64;
    #pragma unroll
    for (int ma = 0; ma < 2; ++ma) {
        #pragma unroll
        for (int r = 0; r < 4; ++r) {
            const int o = (wid * 2 + ma) * 16 + q * 4 + r;
            if (o >= 108) continue;
            const float bz = b_off[o];
            #pragma unroll
            for (int nf = 0; nf < 4; ++nf) {
                const int w = nf * 16 + rl;
                float v = acc[ma][nf][r] + bz;
                if (o < 72)
                    dout[obase + (size_t)o * HW + w] = v;
                else
                    mask_ws[mbase + (size_t)(o - 72) * HW + w] = 1.f / (1.f + expf(-v));
            }
        }
    }
}

// ---------------------------------------------------------------------------
// Kernel 3: deformable conv + residual fuse, MFMA bf16, zero LDS / barriers.
// Round 16: r14 structure EXACTLY, but all gather/coord addresses are 32-bit
// offsets from uniform base pointers (saddr+voffset: 1 VGPR/addr) and
// launch_bounds(256,8) pins VGPR<=64 -> 32 waves/CU (m69 occupancy cliff).
// ---------------------------------------------------------------------------
__global__ __launch_bounds__(256, 8) void dcn_fuse_mfma(
    const float* __restrict__ rife, const unsigned short* __restrict__ dcnwT,
    const float* __restrict__ gamma,
    const unsigned char* __restrict__ vbuf8, const float* __restrict__ mask_ws,
    float* __restrict__ dout)
{
    const int bid = blockIdx.x;
    const int c   = bid & 15;
    const int h   = bid >> 4;
    const int b   = c >> 2;
    const int g   = c & 3;
    const int t    = threadIdx.x;
    const int wv   = t >> 6;
    const int lane = t & 63;
    const int q    = lane >> 4;
    const int rl   = lane & 15;
    const int pix  = wv * 16 + rl;

    const short8* aT = (const short8*)dcnwT;

    f32x4 acc[4];
    #pragma unroll
    for (int ma = 0; ma < 4; ++ma) acc[ma] = (f32x4){0.f, 0.f, 0.f, 0.f};

    // 32-bit element offsets from uniform bases
    const unsigned obA = (unsigned)(4u * 256u * HW) + (unsigned)((b * 72 + g * 18) * HW + h * 64 + pix);
    const unsigned obB = obA + (unsigned)(4u * 72u * HW);
    const unsigned mbA = (unsigned)((b * 36 + g * 9) * HW + h * 64 + pix);
    const unsigned mbB = mbA + (unsigned)(4u * 36u * HW);
    const unsigned vA  = (unsigned)(b * 4096 * 256 + g * 64 + q * 16);
    const unsigned vB  = vA + 4u * 4096u * 256u;

    auto bil = [&](float py, float px, float mv,
                   float& w00, float& w01, float& w10, float& w11,
                   unsigned& o00, unsigned& o01, unsigned& o10, unsigned& o11) {
        const float y0f = floorf(py), x0f = floorf(px);
        const float fy = py - y0f, fx = px - x0f;
        const int y0 = (int)y0f, x0 = (int)x0f;
        const bool vy0 = (y0 >= 0) && (y0 < 64);
        const bool vy1 = (y0 >= -1) && (y0 < 63);
        const bool vx0 = (x0 >= 0) && (x0 < 64);
        const bool vx1 = (x0 >= -1) && (x0 < 63);
        w00 = (1.f - fy) * (1.f - fx) * mv * (float)(vy0 && vx0);
        w01 = (1.f - fy) * fx        * mv * (float)(vy0 && vx1);
        w10 = fy * (1.f - fx)        * mv * (float)(vy1 && vx0);
        w11 = fy * fx                * mv * (float)(vy1 && vx1);
        const int yc0 = min(max(y0, 0), 63),     yc1 = min(max(y0 + 1, 0), 63);
        const int xc0 = min(max(x0, 0), 63),     xc1 = min(max(x0 + 1, 0), 63);
        o00 = (unsigned)(yc0 * 64 + xc0) * 256u;
        o01 = (unsigned)(yc0 * 64 + xc1) * 256u;
        o10 = (unsigned)(yc1 * 64 + xc0) * 256u;
        o11 = (unsigned)(yc1 * 64 + xc1) * 256u;
    };
    // blend 4 fp8 corner vectors (16 ch each) into two bf16x8 fragments
    auto blend8 = [&](uint4 c00, uint4 c01, uint4 c10, uint4 c11,
                      float w00, float w01, float w10, float w11,
                      short8& bf0, short8& bf1) {
        U8 u0, u1;
        {
            f32x2 eL = w00*CVT8(c00.x,false) + w01*CVT8(c01.x,false) + w10*CVT8(c10.x,false) + w11*CVT8(c11.x,false);
            f32x2 eH = w00*CVT8(c00.x,true)  + w01*CVT8(c01.x,true)  + w10*CVT8(c10.x,true)  + w11*CVT8(c11.x,true);
            u0.u[0] = pk_bf16(eL.x, eL.y); u0.u[1] = pk_bf16(eH.x, eH.y);
        }
        {
            f32x2 eL = w00*CVT8(c00.y,false) + w01*CVT8(c01.y,false) + w10*CVT8(c10.y,false) + w11*CVT8(c11.y,false);
            f32x2 eH = w00*CVT8(c00.y,true)  + w01*CVT8(c01.y,true)  + w10*CVT8(c10.y,true)  + w11*CVT8(c11.y,true);
            u0.u[2] = pk_bf16(eL.x, eL.y); u0.u[3] = pk_bf16(eH.x, eH.y);
        }
        {
            f32x2 eL = w00*CVT8(c00.z,false) + w01*CVT8(c01.z,false) + w10*CVT8(c10.z,false) + w11*CVT8(c11.z,false);
            f32x2 eH = w00*CVT8(c00.z,true)  + w01*CVT8(c01.z,true)  + w10*CVT8(c10.z,true)  + w11*CVT8(c11.z,true);
            u1.u[0] = pk_bf16(eL.x, eL.y); u1.u[1] = pk_bf16(eH.x, eH.y);
        }
        {
            f32x2 eL = w00*CVT8(c00.w,false) + w01*CVT8(c01.w,false) + w10*CVT8(c10.w,false) + w11*CVT8(c11.w,false);
            f32x2 eH = w00*CVT8(c00.w,true)  + w01*CVT8(c01.w,true)  + w10*CVT8(c10.w,true)  + w11*CVT8(c11.w,true);
            u1.u[2] = pk_bf16(eL.x, eL.y); u1.u[3] = pk_bf16(eH.x, eH.y);
        }
        bf0 = u0.s; bf1 = u1.s;
    };

    // k=0 coords
    float cyA = dout[obA], cxA = dout[obA + (unsigned)HW], cmA = mask_ws[mbA];
    float cyB = dout[obB], cxB = dout[obB + (unsigned)HW], cmB = mask_ws[mbB];

    for (int k = 0; k < 9; ++k) {
        const int ky = k / 3, kx = k - ky * 3;

        float wA00, wA01, wA10, wA11, wB00, wB01, wB10, wB11;
        unsigned oA00, oA01, oA10, oA11, oB00, oB01, oB10, oB11;
        bil(cyA + (float)(h - 1 + ky), cxA + (float)(pix - 1 + kx), cmA,
            wA00, wA01, wA10, wA11, oA00, oA01, oA10, oA11);
        bil(cyB + (float)(h - 1 + ky), cxB + (float)(pix - 1 + kx), cmB,
            wB00, wB01, wB10, wB11, oB00, oB01, oB10, oB11);

        // depth-1 coord prefetch: always-initialized, rotated at loop end
        float nyA = cyA, nxA = cxA, nmA = cmA;
        float nyB = cyB, nxB = cxB, nmB = cmB;
        if (k < 8) {
            nyA = dout[obA + (unsigned)((k + 1) * 2 * HW)];
            nxA = dout[obA + (unsigned)(((k + 1) * 2 + 1) * HW)];
            nmA = mask_ws[mbA + (unsigned)((k + 1) * HW)];
            nyB = dout[obB + (unsigned)((k + 1) * 2 * HW)];
            nxB = dout[obB + (unsigned)(((k + 1) * 2 + 1) * HW)];
            nmB = mask_ws[mbB + (unsigned)((k + 1) * HW)];
        }

        // A-fragments (bf16, both ks halves): 8 coalesced 1KB wave loads
        short8 af[4][2];
        #pragma unroll
        for (int ma = 0; ma < 4; ++ma)
            #pragma unroll
            for (int ks = 0; ks < 2; ++ks)
                af[ma][ks] = aT[((size_t)((k * 4 + g) * 2 + ks) * 64 + ma * 16 + rl) * 4 + q];

        // 8 fp8 gather loads (both streams, all channels)
        uint4 A00 = *(const uint4*)(vbuf8 + vA + oA00);
        uint4 A01 = *(const uint4*)(vbuf8 + vA + oA01);
        uint4 A10 = *(const uint4*)(vbuf8 + vA + oA10);
        uint4 A11 = *(const uint4*)(vbuf8 + vA + oA11);
        uint4 B00 = *(const uint4*)(vbuf8 + vB + oB00);
        uint4 B01 = *(const uint4*)(vbuf8 + vB + oB01);
        uint4 B10 = *(const uint4*)(vbuf8 + vB + oB10);
        uint4 B11 = *(const uint4*)(vbuf8 + vB + oB11);

        short8 bf0, bf1;
        blend8(A00, A01, A10, A11, wA00, wA01, wA10, wA11, bf0, bf1);
        acc[0] = __builtin_amdgcn_mfma_f32_16x16x32_bf16(af[0][0], bf0, acc[0], 0, 0, 0);
        acc[1] = __builtin_amdgcn_mfma_f32_16x16x32_bf16(af[1][0], bf0, acc[1], 0, 0, 0);
        acc[2] = __builtin_amdgcn_mfma_f32_16x16x32_bf16(af[2][0], bf0, acc[2], 0, 0, 0);
        acc[3] = __builtin_amdgcn_mfma_f32_16x16x32_bf16(af[3][0], bf0, acc[3], 0, 0, 0);
        acc[0] = __builtin_amdgcn_mfma_f32_16x16x32_bf16(af[0][1], bf1, acc[0], 0, 0, 0);
        acc[1] = __builtin_amdgcn_mfma_f32_16x16x32_bf16(af[1][1], bf1, acc[1], 0, 0, 0);
        acc[2] = __builtin_amdgcn_mfma_f32_16x16x32_bf16(af[2][1], bf1, acc[2], 0, 0, 0);
        acc[3] = __builtin_amdgcn_mfma_f32_16x16x32_bf16(af[3][1], bf1, acc[3], 0, 0, 0);
        blend8(B00, B01, B10, B11, wB00, wB01, wB10, wB11, bf0, bf1);
        acc[0] = __builtin_amdgcn_mfma_f32_16x16x32_bf16(af[0][0], bf0, acc[0], 0, 0, 0);
        acc[1] = __builtin_amdgcn_mfma_f32_16x16x32_bf16(af[1][0], bf0, acc[1], 0, 0, 0);
        acc[2] = __builtin_amdgcn_mfma_f32_16x16x32_bf16(af[2][0], bf0, acc[2], 0, 0, 0);
        acc[3] = __builtin_amdgcn_mfma_f32_16x16x32_bf16(af[3][0], bf0, acc[3], 0, 0, 0);
        acc[0] = __builtin_amdgcn_mfma_f32_16x16x32_bf16(af[0][1], bf1, acc[0], 0, 0, 0);
        acc[1] = __builtin_amdgcn_mfma_f32_16x16x32_bf16(af[1][1], bf1, acc[1], 0, 0, 0);
        acc[2] = __builtin_amdgcn_mfma_f32_16x16x32_bf16(af[2][1], bf1, acc[2], 0, 0, 0);
        acc[3] = __builtin_amdgcn_mfma_f32_16x16x32_bf16(af[3][1], bf1, acc[3], 0, 0, 0);

        cyA = nyA; cxA = nxA; cmA = nmA;
        cyB = nyB; cxB = nxB; cmB = nmB;
    }

    const float gm = gamma[0];
    #pragma unroll
    for (int ma = 0; ma < 4; ++ma) {
        #pragma unroll
        for (int r = 0; r < 4; ++r) {
            const int o = g * 64 + ma * 16 + q * 4 + r;
            const unsigned addr = (unsigned)((b * 256 + o) * HW + h * 64 + pix);
            dout[addr] = rife[addr] + gm * acc[ma][r];
        }
    }
}

// ---------------------------------------------------------------------------
extern "C" void kernel_launch(void* const* d_in, const int* in_sizes, int n_in,
                              void* d_out, int out_size, void* d_ws, size_t ws_size,
                              hipStream_t stream)
{
    const float* rife  = (const float*)d_in[0];
    const float* d0    = (const float*)d_in[1];
    const float* d1    = (const float*)d_in[2];
    const float* wq    = (const float*)d_in[3];
    const float* bq    = (const float*)d_in[4];
    const float* wk    = (const float*)d_in[5];
    const float* bk    = (const float*)d_in[6];
    const float* wv    = (const float*)d_in[7];
    const float* bv    = (const float*)d_in[8];
    const float* w_off = (const float*)d_in[9];
    const float* b_off = (const float*)d_in[10];
    const float* dcnw  = (const float*)d_in[11];
    const float* gamma = (const float*)d_in[12];
    float* out = (float*)d_out;
    char* wsb  = (char*)d_ws;

    // ws layout (bytes)
    unsigned short* comb_t = (unsigned short*)(wsb);              // 33,554,432
    unsigned char*  vbuf8  = (unsigned char*)(wsb + 33554432);    //  8,388,608 (fp8)
    float*          mws    = (float*)(wsb + 50331648);            //  4,718,592
    unsigned short* wT2    = (unsigned short*)(wsb + 55050240);   //  1,179,648
    unsigned short* dcnwT  = (unsigned short*)(wsb + 56229888);   //    294,912
    unsigned short* xT     = (unsigned short*)(wsb + 56524800);   // 25,165,824
    unsigned short* wqkvT  = (unsigned short*)(wsb + 81690624);   //    393,216
    // total: ~82.1 MB

    prep_all<<<3648, 256, 0, stream>>>(w_off, dcnw, wq, wk, wv, wT2, dcnwT, wqkvT);
    xprep<<<dim3(64, 12), 256, 0, stream>>>(rife, d0, d1, xT);
    qkv_mfma<<<dim3(64, 3, 8), 256, 0, stream>>>(xT, wqkvT, bq, bk, bv, comb_t, vbuf8);
    offconv_mfma<<<512, 256, 0, stream>>>(comb_t, wT2, b_off, out, mws);
    dcn_fuse_mfma<<<1024, 256, 0, stream>>>(rife, dcnwT, gamma, vbuf8, mws, out);
}

// Round 17
// 200.055 us; speedup vs baseline: 1.3521x; 1.3521x over previous
//
#include <hip/hip_runtime.h>
#include <math.h>

#define HW   4096
#define CDIM 256

typedef float f32x4  __attribute__((ext_vector_type(4)));
typedef float f32x2  __attribute__((ext_vector_type(2)));
typedef short short8 __attribute__((ext_vector_type(8)));

// d_out layout (float offsets)
#define FUSED_SZ (4ULL*256*HW)
#define OFF_SZ   (4ULL*72*HW)

static __device__ __forceinline__ unsigned short f2b(float f) {
    unsigned u = __float_as_uint(f);
    unsigned r = (u + 0x7fffu + ((u >> 16) & 1u)) >> 16;
    return (unsigned short)r;
}
static __device__ __forceinline__ float b2f(short h) {
    return __uint_as_float(((unsigned)(unsigned short)h) << 16);
}
// packed f32x2 -> bf16x2 (lo = a, hi = b), RNE in HW
static __device__ __forceinline__ unsigned pk_bf16(float a, float b) {
    unsigned r;
    asm("v_cvt_pk_bf16_f32 %0, %1, %2" : "=v"(r) : "v"(a), "v"(b));
    return r;
}
union U8 { unsigned u[4]; short8 s; };

// fp8x2 -> f32x2 unpack; word-select must be a LITERAL (builtin constraint)
#define CVT8(a, HI) ((f32x2)__builtin_amdgcn_cvt_pk_f32_fp8((int)(a), HI))

// ---------------------------------------------------------------------------
// Kernel 0: fused one-time weight preps (3 ranges in one launch).
// ---------------------------------------------------------------------------
__global__ __launch_bounds__(256) void prep_all(
    const float* __restrict__ w_off, const float* __restrict__ dcn_w,
    const float* __restrict__ wq, const float* __restrict__ wk,
    const float* __restrict__ wv,
    unsigned short* __restrict__ wT2, unsigned short* __restrict__ dcnwT,
    unsigned short* __restrict__ wqkvT)
{
    const int bid = blockIdx.x;
    if (bid < 2304) {
        int idx = bid * 256 + threadIdx.x;
        int kk  = idx / (128 * 512);
        int rem = idx - kk * 128 * 512;
        int o = rem >> 9;
        int c = rem & 511;
        float v = (o < 108) ? w_off[((size_t)o * 512 + c) * 9 + kk] : 0.f;
        size_t flat = ((size_t)(kk * 16 + (c >> 5)) * 128 + o) * 32 + (c & 31);
        wT2[flat] = f2b(v);
    } else if (bid < 2880) {
        int idx = (bid - 2304) * 256 + threadIdx.x;
        if (idx < 9 * 256 * 64) {
            int k   = idx / (256 * 64);
            int rem = idx - k * 256 * 64;
            int og = rem >> 6;
            int i  = rem & 63;
            int g = og >> 6, ol = og & 63;
            size_t flat = ((size_t)((k * 4 + g) * 2 + (i >> 5)) * 64 + ol) * 32 + (i & 31);
            dcnwT[flat] = f2b(dcn_w[((size_t)og * 64 + i) * 9 + k]);
        }
    } else {
        int idx = (bid - 2880) * 256 + threadIdx.x;   // 768*256
        int o = idx >> 8;
        int c = idx & 255;
        float v = (o < 256) ? wq[(size_t)o * 256 + c]
                : (o < 512) ? wk[(size_t)(o - 256) * 256 + c]
                            : wv[(size_t)(o - 512) * 256 + c];
        wqkvT[idx] = f2b(v);
    }
}

// ---------------------------------------------------------------------------
// Kernel 0d: transpose 12 input images NCHW f32 -> NHWC bf16  xT[12][4096][256]
// ---------------------------------------------------------------------------
__global__ __launch_bounds__(256) void xprep(
    const float* __restrict__ rife, const float* __restrict__ d0,
    const float* __restrict__ d1, unsigned short* __restrict__ xT)
{
    const int pix0 = blockIdx.x * 64;
    const int img  = blockIdx.y;
    const int t    = threadIdx.x;

    const float* src = (img < 4) ? rife + (size_t)img * CDIM * HW
                     : (img < 8) ? d0 + (size_t)(img - 4) * CDIM * HW
                                 : d1 + (size_t)(img - 8) * CDIM * HW;
    unsigned short* dst = xT + (size_t)img * 4096 * 256;

    __shared__ float tile[64][65];

    for (int c0 = 0; c0 < 256; c0 += 64) {
        #pragma unroll
        for (int r = 0; r < 16; ++r) {
            int idx = t + r * 256;
            int c = idx >> 6, pp = idx & 63;
            tile[c][pp] = src[(size_t)(c0 + c) * HW + pix0 + pp];
        }
        __syncthreads();
        const int pix = t >> 2, cq = t & 3;
        const int cb = cq * 16;
        uint4 p0, p1;
        p0.x = pk_bf16(tile[cb+0][pix],  tile[cb+1][pix]);
        p0.y = pk_bf16(tile[cb+2][pix],  tile[cb+3][pix]);
        p0.z = pk_bf16(tile[cb+4][pix],  tile[cb+5][pix]);
        p0.w = pk_bf16(tile[cb+6][pix],  tile[cb+7][pix]);
        p1.x = pk_bf16(tile[cb+8][pix],  tile[cb+9][pix]);
        p1.y = pk_bf16(tile[cb+10][pix], tile[cb+11][pix]);
        p1.z = pk_bf16(tile[cb+12][pix], tile[cb+13][pix]);
        p1.w = pk_bf16(tile[cb+14][pix], tile[cb+15][pix]);
        unsigned short* p = dst + (size_t)(pix0 + pix) * 256 + c0 + cb;
        *(uint4*)p = p0;
        *(uint4*)(p + 8) = p1;
        __syncthreads();
    }
}

// ---------------------------------------------------------------------------
// Kernel 1: QKV 1x1 convs as pure-register MFMA GEMM (no LDS, no barriers).
//   Q,K -> comb_t bf16 NHWC.   V -> vbuf8 fp8-e4m3, channel-PERMUTED per
//   64-ch group: channel l = ks*32 + qq*8 + j  ->  position qq*16 + ks*8 + j.
// ---------------------------------------------------------------------------
__global__ __launch_bounds__(256) void qkv_mfma(
    const unsigned short* __restrict__ xT,
    const unsigned short* __restrict__ wqkvT,
    const float* __restrict__ bq, const float* __restrict__ bk,
    const float* __restrict__ bv,
    unsigned short* __restrict__ comb_t, unsigned char* __restrict__ vbuf8)
{
    const int pix0 = blockIdx.x * 64;
    const int type = blockIdx.y;
    const int s    = blockIdx.z;
    const int t    = threadIdx.x;
    const int wvi  = t >> 6;
    const int lane = t & 63;
    const int q    = lane >> 4;
    const int rl   = lane & 15;

    const int img = (type == 0) ? (s & 3) : (4 + s);
    const short8* X = (const short8*)(xT + (size_t)img * 4096 * 256);
    const short8* W = (const short8*)(wqkvT + (size_t)(type * 256 + wvi * 64) * 256);
    const float* bias = (type == 0) ? bq : (type == 1) ? bk : bv;

    f32x4 acc[4][4];
    #pragma unroll
    for (int mf = 0; mf < 4; ++mf)
        #pragma unroll
        for (int nf = 0; nf < 4; ++nf)
            acc[mf][nf] = (f32x4){0.f, 0.f, 0.f, 0.f};

    #pragma unroll
    for (int c8 = 0; c8 < 32; c8 += 4) {
        short8 a[4], b[4];
        #pragma unroll
        for (int mf = 0; mf < 4; ++mf)
            a[mf] = W[(size_t)(mf * 16 + rl) * 32 + c8 + q];
        #pragma unroll
        for (int nf = 0; nf < 4; ++nf)
            b[nf] = X[(size_t)(pix0 + nf * 16 + rl) * 32 + c8 + q];
        #pragma unroll
        for (int mf = 0; mf < 4; ++mf)
            #pragma unroll
            for (int nf = 0; nf < 4; ++nf)
                acc[mf][nf] = __builtin_amdgcn_mfma_f32_16x16x32_bf16(a[mf], b[nf], acc[mf][nf], 0, 0, 0);
    }

    if (type < 2) {
        unsigned short* dst = comb_t + (size_t)s * 4096 * 512 + type * 256;
        #pragma unroll
        for (int mf = 0; mf < 4; ++mf) {
            const int o_loc = wvi * 64 + mf * 16 + q * 4;
            const float4 bz = *(const float4*)(bias + o_loc);
            #pragma unroll
            for (int nf = 0; nf < 4; ++nf) {
                const int pix = pix0 + nf * 16 + rl;
                uint2 pk;
                pk.x = pk_bf16(acc[mf][nf][0] + bz.x, acc[mf][nf][1] + bz.y);
                pk.y = pk_bf16(acc[mf][nf][2] + bz.z, acc[mf][nf][3] + bz.w);
                *(uint2*)(dst + (size_t)pix * 512 + o_loc) = pk;
            }
        }
    } else {
        unsigned char* dst8 = vbuf8 + (size_t)s * 4096 * 256;
        #pragma unroll
        for (int mf = 0; mf < 4; ++mf) {
            const int l = mf * 16 + q * 4;          // local ch within 64-group
            const int p = wvi * 64 + ((l >> 3) & 3) * 16 + (l >> 5) * 8 + (l & 7);
            const float4 bz = *(const float4*)(bias + wvi * 64 + l);
            #pragma unroll
            for (int nf = 0; nf < 4; ++nf) {
                const int pix = pix0 + nf * 16 + rl;
                int u = __builtin_amdgcn_cvt_pk_fp8_f32(acc[mf][nf][0] + bz.x,
                                                        acc[mf][nf][1] + bz.y, 0, false);
                u = __builtin_amdgcn_cvt_pk_fp8_f32(acc[mf][nf][2] + bz.z,
                                                    acc[mf][nf][3] + bz.w, u, true);
                *(unsigned*)(dst8 + (size_t)pix * 256 + p) = (unsigned)u;
            }
        }
    }
}

// ---------------------------------------------------------------------------
// Kernel 2: 3x3 conv 512->108 as implicit GEMM on MFMA bf16 (r10 full-row form).
// ---------------------------------------------------------------------------
__global__ __launch_bounds__(256) void offconv_mfma(
    const unsigned short* __restrict__ comb_t,
    const unsigned short* __restrict__ wT2,
    const float* __restrict__ b_off,
    float* __restrict__ dout, float* __restrict__ mask_ws)
{
    const int bid = blockIdx.x;
    const int s = bid & 7;          // XCD = linear_bid % 8 = s
    const int h = bid >> 3;
    const int t = threadIdx.x;
    const int lane = t & 63;
    const int wid  = t >> 6;
    const int q    = lane >> 4;
    const int rl   = lane & 15;

    __shared__ __align__(16) unsigned short tb[2][792 * 8];

    const short8* cbv = (const short8*)comb_t + (size_t)s * 4096 * 64;
    const short8* wv  = (const short8*)wT2;

    const int i1 = t + 256, i2 = t + 512, i3 = t + 768;

    auto sload = [&](int idx, int c8) -> short8 {
        int x = idx >> 2, cq = idx & 3;
        int ky = x / 66, xx = x - ky * 66;
        int hh = h + ky - 1, gx = xx - 1;
        short8 v = {0, 0, 0, 0, 0, 0, 0, 0};
        if (hh >= 0 && hh < 64 && gx >= 0 && gx < 64)
            v = cbv[(size_t)(hh * 64 + gx) * 64 + c8 + cq];
        return v;
    };
    auto swrite = [&](unsigned short* buf, int idx, short8 v) {
        int x = idx >> 2, cq = idx & 3;
        int qs = cq ^ ((x >> 1) & 3);
        *((short8*)buf + x * 4 + qs) = v;
    };

    f32x4 acc[2][4];
    #pragma unroll
    for (int ma = 0; ma < 2; ++ma)
        #pragma unroll
        for (int nf = 0; nf < 4; ++nf)
            acc[ma][nf] = (f32x4){0.f, 0.f, 0.f, 0.f};

    short8 r0 = sload(t, 0), r1 = sload(i1, 0), r2 = sload(i2, 0);
    short8 r3 = {0,0,0,0,0,0,0,0};
    if (i3 < 792) r3 = sload(i3, 0);
    swrite(tb[0], t, r0); swrite(tb[0], i1, r1); swrite(tb[0], i2, r2);
    if (i3 < 792) swrite(tb[0], i3, r3);
    __syncthreads();

    for (int sl = 0; sl < 16; ++sl) {
        const int c8 = sl * 4;
        if (sl < 15) {
            r0 = sload(t, c8 + 4); r1 = sload(i1, c8 + 4); r2 = sload(i2, c8 + 4);
            if (i3 < 792) r3 = sload(i3, c8 + 4);
        }
        short8 a[2][9];
        #pragma unroll
        for (int ma = 0; ma < 2; ++ma) {
            const int o = (wid * 2 + ma) * 16 + rl;
            #pragma unroll
            for (int kk = 0; kk < 9; ++kk)
                a[ma][kk] = wv[((size_t)(kk * 16 + sl) * 128 + o) * 4 + q];
        }
        const unsigned short* bufc = tb[sl & 1];
        #pragma unroll
        for (int kk = 0; kk < 9; ++kk) {
            const int ky = kk / 3, kx = kk % 3;
            #pragma unroll
            for (int nf = 0; nf < 4; ++nf) {
                const int xr = ky * 66 + nf * 16 + rl + kx;
                short8 b = *((const short8*)bufc + xr * 4 + (q ^ ((xr >> 1) & 3)));
                acc[0][nf] = __builtin_amdgcn_mfma_f32_16x16x32_bf16(a[0][kk], b, acc[0][nf], 0, 0, 0);
                acc[1][nf] = __builtin_amdgcn_mfma_f32_16x16x32_bf16(a[1][kk], b, acc[1][nf], 0, 0, 0);
            }
        }
        if (sl < 15) {
            unsigned short* bufn = tb[(sl + 1) & 1];
            swrite(bufn, t, r0); swrite(bufn, i1, r1); swrite(bufn, i2, r2);
            if (i3 < 792) swrite(bufn, i3, r3);
        }
        __syncthreads();
    }

    const size_t obase = FUSED_SZ + (s < 4 ? 0 : OFF_SZ) + (size_t)(s & 3) * 72 * HW + (size_t)h * 64;
    const size_t mbase = (size_t)s * 36 * HW + (size_t)h * 64;
    #pragma unroll
    for (int ma = 0; ma < 2; ++ma) {
        #pragma unroll
        for (int r = 0; r < 4; ++r) {
            const int o = (wid * 2 + ma) * 16 + q * 4 + r;
            if (o >= 108) continue;
            const float bz = b_off[o];
            #pragma unroll
            for (int nf = 0; nf < 4; ++nf) {
                const int w = nf * 16 + rl;
                float v = acc[ma][nf][r] + bz;
                if (o < 72)
                    dout[obase + (size_t)o * HW + w] = v;
                else
                    mask_ws[mbase + (size_t)(o - 72) * HW + w] = 1.f / (1.f + expf(-v));
            }
        }
    }
}

// ---------------------------------------------------------------------------
// Kernel 3: deformable conv + residual fuse, MFMA bf16, zero LDS / barriers.
// Round 17: r14 structure + 32-bit offset addressing (structural VGPR diet),
// NO launch-bounds cap (r8/r16 proved caps spill).  If natural VGPR lands
// <=64 occupancy doubles for free; else identical to the passing r14.
// ---------------------------------------------------------------------------
__global__ __launch_bounds__(256) void dcn_fuse_mfma(
    const float* __restrict__ rife, const unsigned short* __restrict__ dcnwT,
    const float* __restrict__ gamma,
    const unsigned char* __restrict__ vbuf8, const float* __restrict__ mask_ws,
    float* __restrict__ dout)
{
    const int bid = blockIdx.x;
    const int c   = bid & 15;
    const int h   = bid >> 4;
    const int b   = c >> 2;
    const int g   = c & 3;
    const int t    = threadIdx.x;
    const int wv   = t >> 6;
    const int lane = t & 63;
    const int q    = lane >> 4;
    const int rl   = lane & 15;
    const int pix  = wv * 16 + rl;

    const short8* aT = (const short8*)dcnwT;

    f32x4 acc[4];
    #pragma unroll
    for (int ma = 0; ma < 4; ++ma) acc[ma] = (f32x4){0.f, 0.f, 0.f, 0.f};

    // 32-bit element offsets from uniform bases
    const unsigned obA = (unsigned)(4u * 256u * HW) + (unsigned)((b * 72 + g * 18) * HW + h * 64 + pix);
    const unsigned obB = obA + (unsigned)(4u * 72u * HW);
    const unsigned mbA = (unsigned)((b * 36 + g * 9) * HW + h * 64 + pix);
    const unsigned mbB = mbA + (unsigned)(4u * 36u * HW);
    const unsigned vA  = (unsigned)(b * 4096 * 256 + g * 64 + q * 16);
    const unsigned vB  = vA + 4u * 4096u * 256u;

    auto bil = [&](float py, float px, float mv,
                   float& w00, float& w01, float& w10, float& w11,
                   unsigned& o00, unsigned& o01, unsigned& o10, unsigned& o11) {
        const float y0f = floorf(py), x0f = floorf(px);
        const float fy = py - y0f, fx = px - x0f;
        const int y0 = (int)y0f, x0 = (int)x0f;
        const bool vy0 = (y0 >= 0) && (y0 < 64);
        const bool vy1 = (y0 >= -1) && (y0 < 63);
        const bool vx0 = (x0 >= 0) && (x0 < 64);
        const bool vx1 = (x0 >= -1) && (x0 < 63);
        w00 = (1.f - fy) * (1.f - fx) * mv * (float)(vy0 && vx0);
        w01 = (1.f - fy) * fx        * mv * (float)(vy0 && vx1);
        w10 = fy * (1.f - fx)        * mv * (float)(vy1 && vx0);
        w11 = fy * fx                * mv * (float)(vy1 && vx1);
        const int yc0 = min(max(y0, 0), 63),     yc1 = min(max(y0 + 1, 0), 63);
        const int xc0 = min(max(x0, 0), 63),     xc1 = min(max(x0 + 1, 0), 63);
        o00 = (unsigned)(yc0 * 64 + xc0) * 256u;
        o01 = (unsigned)(yc0 * 64 + xc1) * 256u;
        o10 = (unsigned)(yc1 * 64 + xc0) * 256u;
        o11 = (unsigned)(yc1 * 64 + xc1) * 256u;
    };
    // blend 4 fp8 corner vectors (16 ch each) into two bf16x8 fragments
    auto blend8 = [&](uint4 c00, uint4 c01, uint4 c10, uint4 c11,
                      float w00, float w01, float w10, float w11,
                      short8& bf0, short8& bf1) {
        U8 u0, u1;
        {
            f32x2 eL = w00*CVT8(c00.x,false) + w01*CVT8(c01.x,false) + w10*CVT8(c10.x,false) + w11*CVT8(c11.x,false);
            f32x2 eH = w00*CVT8(c00.x,true)  + w01*CVT8(c01.x,true)  + w10*CVT8(c10.x,true)  + w11*CVT8(c11.x,true);
            u0.u[0] = pk_bf16(eL.x, eL.y); u0.u[1] = pk_bf16(eH.x, eH.y);
        }
        {
            f32x2 eL = w00*CVT8(c00.y,false) + w01*CVT8(c01.y,false) + w10*CVT8(c10.y,false) + w11*CVT8(c11.y,false);
            f32x2 eH = w00*CVT8(c00.y,true)  + w01*CVT8(c01.y,true)  + w10*CVT8(c10.y,true)  + w11*CVT8(c11.y,true);
            u0.u[2] = pk_bf16(eL.x, eL.y); u0.u[3] = pk_bf16(eH.x, eH.y);
        }
        {
            f32x2 eL = w00*CVT8(c00.z,false) + w01*CVT8(c01.z,false) + w10*CVT8(c10.z,false) + w11*CVT8(c11.z,false);
            f32x2 eH = w00*CVT8(c00.z,true)  + w01*CVT8(c01.z,true)  + w10*CVT8(c10.z,true)  + w11*CVT8(c11.z,true);
            u1.u[0] = pk_bf16(eL.x, eL.y); u1.u[1] = pk_bf16(eH.x, eH.y);
        }
        {
            f32x2 eL = w00*CVT8(c00.w,false) + w01*CVT8(c01.w,false) + w10*CVT8(c10.w,false) + w11*CVT8(c11.w,false);
            f32x2 eH = w00*CVT8(c00.w,true)  + w01*CVT8(c01.w,true)  + w10*CVT8(c10.w,true)  + w11*CVT8(c11.w,true);
            u1.u[2] = pk_bf16(eL.x, eL.y); u1.u[3] = pk_bf16(eH.x, eH.y);
        }
        bf0 = u0.s; bf1 = u1.s;
    };

    // k=0 coords
    float cyA = dout[obA], cxA = dout[obA + (unsigned)HW], cmA = mask_ws[mbA];
    float cyB = dout[obB], cxB = dout[obB + (unsigned)HW], cmB = mask_ws[mbB];

    for (int k = 0; k < 9; ++k) {
        const int ky = k / 3, kx = k - ky * 3;

        float wA00, wA01, wA10, wA11, wB00, wB01, wB10, wB11;
        unsigned oA00, oA01, oA10, oA11, oB00, oB01, oB10, oB11;
        bil(cyA + (float)(h - 1 + ky), cxA + (float)(pix - 1 + kx), cmA,
            wA00, wA01, wA10, wA11, oA00, oA01, oA10, oA11);
        bil(cyB + (float)(h - 1 + ky), cxB + (float)(pix - 1 + kx), cmB,
            wB00, wB01, wB10, wB11, oB00, oB01, oB10, oB11);

        // depth-1 coord prefetch: always-initialized, rotated at loop end
        float nyA = cyA, nxA = cxA, nmA = cmA;
        float nyB = cyB, nxB = cxB, nmB = cmB;
        if (k < 8) {
            nyA = dout[obA + (unsigned)((k + 1) * 2 * HW)];
            nxA = dout[obA + (unsigned)(((k + 1) * 2 + 1) * HW)];
            nmA = mask_ws[mbA + (unsigned)((k + 1) * HW)];
            nyB = dout[obB + (unsigned)((k + 1) * 2 * HW)];
            nxB = dout[obB + (unsigned)(((k + 1) * 2 + 1) * HW)];
            nmB = mask_ws[mbB + (unsigned)((k + 1) * HW)];
        }

        // A-fragments (bf16, both ks halves): 8 coalesced 1KB wave loads
        short8 af[4][2];
        #pragma unroll
        for (int ma = 0; ma < 4; ++ma)
            #pragma unroll
            for (int ks = 0; ks < 2; ++ks)
                af[ma][ks] = aT[((size_t)((k * 4 + g) * 2 + ks) * 64 + ma * 16 + rl) * 4 + q];

        // 8 fp8 gather loads (both streams, all channels)
        uint4 A00 = *(const uint4*)(vbuf8 + vA + oA00);
        uint4 A01 = *(const uint4*)(vbuf8 + vA + oA01);
        uint4 A10 = *(const uint4*)(vbuf8 + vA + oA10);
        uint4 A11 = *(const uint4*)(vbuf8 + vA + oA11);
        uint4 B00 = *(const uint4*)(vbuf8 + vB + oB00);
        uint4 B01 = *(const uint4*)(vbuf8 + vB + oB01);
        uint4 B10 = *(const uint4*)(vbuf8 + vB + oB10);
        uint4 B11 = *(const uint4*)(vbuf8 + vB + oB11);

        short8 bf0, bf1;
        blend8(A00, A01, A10, A11, wA00, wA01, wA10, wA11, bf0, bf1);
        acc[0] = __builtin_amdgcn_mfma_f32_16x16x32_bf16(af[0][0], bf0, acc[0], 0, 0, 0);
        acc[1] = __builtin_amdgcn_mfma_f32_16x16x32_bf16(af[1][0], bf0, acc[1], 0, 0, 0);
        acc[2] = __builtin_amdgcn_mfma_f32_16x16x32_bf16(af[2][0], bf0, acc[2], 0, 0, 0);
        acc[3] = __builtin_amdgcn_mfma_f32_16x16x32_bf16(af[3][0], bf0, acc[3], 0, 0, 0);
        acc[0] = __builtin_amdgcn_mfma_f32_16x16x32_bf16(af[0][1], bf1, acc[0], 0, 0, 0);
        acc[1] = __builtin_amdgcn_mfma_f32_16x16x32_bf16(af[1][1], bf1, acc[1], 0, 0, 0);
        acc[2] = __builtin_amdgcn_mfma_f32_16x16x32_bf16(af[2][1], bf1, acc[2], 0, 0, 0);
        acc[3] = __builtin_amdgcn_mfma_f32_16x16x32_bf16(af[3][1], bf1, acc[3], 0, 0, 0);
        blend8(B00, B01, B10, B11, wB00, wB01, wB10, wB11, bf0, bf1);
        acc[0] = __builtin_amdgcn_mfma_f32_16x16x32_bf16(af[0][0], bf0, acc[0], 0, 0, 0);
        acc[1] = __builtin_amdgcn_mfma_f32_16x16x32_bf16(af[1][0], bf0, acc[1], 0, 0, 0);
        acc[2] = __builtin_amdgcn_mfma_f32_16x16x32_bf16(af[2][0], bf0, acc[2], 0, 0, 0);
        acc[3] = __builtin_amdgcn_mfma_f32_16x16x32_bf16(af[3][0], bf0, acc[3], 0, 0, 0);
        acc[0] = __builtin_amdgcn_mfma_f32_16x16x32_bf16(af[0][1], bf1, acc[0], 0, 0, 0);
        acc[1] = __builtin_amdgcn_mfma_f32_16x16x32_bf16(af[1][1], bf1, acc[1], 0, 0, 0);
        acc[2] = __builtin_amdgcn_mfma_f32_16x16x32_bf16(af[2][1], bf1, acc[2], 0, 0, 0);
        acc[3] = __builtin_amdgcn_mfma_f32_16x16x32_bf16(af[3][1], bf1, acc[3], 0, 0, 0);

        cyA = nyA; cxA = nxA; cmA = nmA;
        cyB = nyB; cxB = nxB; cmB = nmB;
    }

    const float gm = gamma[0];
    #pragma unroll
    for (int ma = 0; ma < 4; ++ma) {
        #pragma unroll
        for (int r = 0; r < 4; ++r) {
            const int o = g * 64 + ma * 16 + q * 4 + r;
            const unsigned addr = (unsigned)((b * 256 + o) * HW + h * 64 + pix);
            dout[addr] = rife[addr] + gm * acc[ma][r];
        }
    }
}

// ---------------------------------------------------------------------------
extern "C" void kernel_launch(void* const* d_in, const int* in_sizes, int n_in,
                              void* d_out, int out_size, void* d_ws, size_t ws_size,
                              hipStream_t stream)
{
    const float* rife  = (const float*)d_in[0];
    const float* d0    = (const float*)d_in[1];
    const float* d1    = (const float*)d_in[2];
    const float* wq    = (const float*)d_in[3];
    const float* bq    = (const float*)d_in[4];
    const float* wk    = (const float*)d_in[5];
    const float* bk    = (const float*)d_in[6];
    const float* wv    = (const float*)d_in[7];
    const float* bv    = (const float*)d_in[8];
    const float* w_off = (const float*)d_in[9];
    const float* b_off = (const float*)d_in[10];
    const float* dcnw  = (const float*)d_in[11];
    const float* gamma = (const float*)d_in[12];
    float* out = (float*)d_out;
    char* wsb  = (char*)d_ws;

    // ws layout (bytes)
    unsigned short* comb_t = (unsigned short*)(wsb);              // 33,554,432
    unsigned char*  vbuf8  = (unsigned char*)(wsb + 33554432);    //  8,388,608 (fp8)
    float*          mws    = (float*)(wsb + 50331648);            //  4,718,592
    unsigned short* wT2    = (unsigned short*)(wsb + 55050240);   //  1,179,648
    unsigned short* dcnwT  = (unsigned short*)(wsb + 56229888);   //    294,912
    unsigned short* xT     = (unsigned short*)(wsb + 56524800);   // 25,165,824
    unsigned short* wqkvT  = (unsigned short*)(wsb + 81690624);   //    393,216
    // total: ~82.1 MB

    prep_all<<<3648, 256, 0, stream>>>(w_off, dcnw, wq, wk, wv, wT2, dcnwT, wqkvT);
    xprep<<<dim3(64, 12), 256, 0, stream>>>(rife, d0, d1, xT);
    qkv_mfma<<<dim3(64, 3, 8), 256, 0, stream>>>(xT, wqkvT, bq, bk, bv, comb_t, vbuf8);
    offconv_mfma<<<512, 256, 0, stream>>>(comb_t, wT2, b_off, out, mws);
    dcn_fuse_mfma<<<1024, 256, 0, stream>>>(rife, dcnwT, gamma, vbuf8, mws, out);
}

// Round 18
// 188.154 us; speedup vs baseline: 1.4376x; 1.0633x over previous
//
#include <hip/hip_runtime.h>
#include <math.h>

#define HW   4096
#define CDIM 256

typedef float f32x4  __attribute__((ext_vector_type(4)));
typedef float f32x2  __attribute__((ext_vector_type(2)));
typedef short short8 __attribute__((ext_vector_type(8)));

// d_out layout (float offsets)
#define FUSED_SZ (4ULL*256*HW)
#define OFF_SZ   (4ULL*72*HW)

static __device__ __forceinline__ unsigned short f2b(float f) {
    unsigned u = __float_as_uint(f);
    unsigned r = (u + 0x7fffu + ((u >> 16) & 1u)) >> 16;
    return (unsigned short)r;
}
static __device__ __forceinline__ float b2f(short h) {
    return __uint_as_float(((unsigned)(unsigned short)h) << 16);
}
// packed f32x2 -> bf16x2 (lo = a, hi = b), RNE in HW
static __device__ __forceinline__ unsigned pk_bf16(float a, float b) {
    unsigned r;
    asm("v_cvt_pk_bf16_f32 %0, %1, %2" : "=v"(r) : "v"(a), "v"(b));
    return r;
}
union U8 { unsigned u[4]; short8 s; };

// fp8x2 -> f32x2 unpack; word-select must be a LITERAL (builtin constraint)
#define CVT8(a, HI) ((f32x2)__builtin_amdgcn_cvt_pk_f32_fp8((int)(a), HI))

// ---------------------------------------------------------------------------
// Kernel 0: fused one-time weight preps (3 ranges in one launch).
// ---------------------------------------------------------------------------
__global__ __launch_bounds__(256) void prep_all(
    const float* __restrict__ w_off, const float* __restrict__ dcn_w,
    const float* __restrict__ wq, const float* __restrict__ wk,
    const float* __restrict__ wv,
    unsigned short* __restrict__ wT2, unsigned short* __restrict__ dcnwT,
    unsigned short* __restrict__ wqkvT)
{
    const int bid = blockIdx.x;
    if (bid < 2304) {
        int idx = bid * 256 + threadIdx.x;
        int kk  = idx / (128 * 512);
        int rem = idx - kk * 128 * 512;
        int o = rem >> 9;
        int c = rem & 511;
        float v = (o < 108) ? w_off[((size_t)o * 512 + c) * 9 + kk] : 0.f;
        size_t flat = ((size_t)(kk * 16 + (c >> 5)) * 128 + o) * 32 + (c & 31);
        wT2[flat] = f2b(v);
    } else if (bid < 2880) {
        int idx = (bid - 2304) * 256 + threadIdx.x;
        if (idx < 9 * 256 * 64) {
            int k   = idx / (256 * 64);
            int rem = idx - k * 256 * 64;
            int og = rem >> 6;
            int i  = rem & 63;
            int g = og >> 6, ol = og & 63;
            size_t flat = ((size_t)((k * 4 + g) * 2 + (i >> 5)) * 64 + ol) * 32 + (i & 31);
            dcnwT[flat] = f2b(dcn_w[((size_t)og * 64 + i) * 9 + k]);
        }
    } else {
        int idx = (bid - 2880) * 256 + threadIdx.x;   // 768*256
        int o = idx >> 8;
        int c = idx & 255;
        float v = (o < 256) ? wq[(size_t)o * 256 + c]
                : (o < 512) ? wk[(size_t)(o - 256) * 256 + c]
                            : wv[(size_t)(o - 512) * 256 + c];
        wqkvT[idx] = f2b(v);
    }
}

// ---------------------------------------------------------------------------
// Kernel 0d: transpose 12 input images NCHW f32 -> NHWC bf16  xT[12][4096][256]
// ---------------------------------------------------------------------------
__global__ __launch_bounds__(256) void xprep(
    const float* __restrict__ rife, const float* __restrict__ d0,
    const float* __restrict__ d1, unsigned short* __restrict__ xT)
{
    const int pix0 = blockIdx.x * 64;
    const int img  = blockIdx.y;
    const int t    = threadIdx.x;

    const float* src = (img < 4) ? rife + (size_t)img * CDIM * HW
                     : (img < 8) ? d0 + (size_t)(img - 4) * CDIM * HW
                                 : d1 + (size_t)(img - 8) * CDIM * HW;
    unsigned short* dst = xT + (size_t)img * 4096 * 256;

    __shared__ float tile[64][65];

    for (int c0 = 0; c0 < 256; c0 += 64) {
        #pragma unroll
        for (int r = 0; r < 16; ++r) {
            int idx = t + r * 256;
            int c = idx >> 6, pp = idx & 63;
            tile[c][pp] = src[(size_t)(c0 + c) * HW + pix0 + pp];
        }
        __syncthreads();
        const int pix = t >> 2, cq = t & 3;
        const int cb = cq * 16;
        uint4 p0, p1;
        p0.x = pk_bf16(tile[cb+0][pix],  tile[cb+1][pix]);
        p0.y = pk_bf16(tile[cb+2][pix],  tile[cb+3][pix]);
        p0.z = pk_bf16(tile[cb+4][pix],  tile[cb+5][pix]);
        p0.w = pk_bf16(tile[cb+6][pix],  tile[cb+7][pix]);
        p1.x = pk_bf16(tile[cb+8][pix],  tile[cb+9][pix]);
        p1.y = pk_bf16(tile[cb+10][pix], tile[cb+11][pix]);
        p1.z = pk_bf16(tile[cb+12][pix], tile[cb+13][pix]);
        p1.w = pk_bf16(tile[cb+14][pix], tile[cb+15][pix]);
        unsigned short* p = dst + (size_t)(pix0 + pix) * 256 + c0 + cb;
        *(uint4*)p = p0;
        *(uint4*)(p + 8) = p1;
        __syncthreads();
    }
}

// ---------------------------------------------------------------------------
// Kernel 1: QKV 1x1 convs as pure-register MFMA GEMM (no LDS, no barriers).
//   Q,K -> comb_t bf16 NHWC.   V -> vbuf8 fp8-e4m3, channel-PERMUTED per
//   64-ch group: channel l = ks*32 + qq*8 + j  ->  position qq*16 + ks*8 + j.
// ---------------------------------------------------------------------------
__global__ __launch_bounds__(256) void qkv_mfma(
    const unsigned short* __restrict__ xT,
    const unsigned short* __restrict__ wqkvT,
    const float* __restrict__ bq, const float* __restrict__ bk,
    const float* __restrict__ bv,
    unsigned short* __restrict__ comb_t, unsigned char* __restrict__ vbuf8)
{
    const int pix0 = blockIdx.x * 64;
    const int type = blockIdx.y;
    const int s    = blockIdx.z;
    const int t    = threadIdx.x;
    const int wvi  = t >> 6;
    const int lane = t & 63;
    const int q    = lane >> 4;
    const int rl   = lane & 15;

    const int img = (type == 0) ? (s & 3) : (4 + s);
    const short8* X = (const short8*)(xT + (size_t)img * 4096 * 256);
    const short8* W = (const short8*)(wqkvT + (size_t)(type * 256 + wvi * 64) * 256);
    const float* bias = (type == 0) ? bq : (type == 1) ? bk : bv;

    f32x4 acc[4][4];
    #pragma unroll
    for (int mf = 0; mf < 4; ++mf)
        #pragma unroll
        for (int nf = 0; nf < 4; ++nf)
            acc[mf][nf] = (f32x4){0.f, 0.f, 0.f, 0.f};

    #pragma unroll
    for (int c8 = 0; c8 < 32; c8 += 4) {
        short8 a[4], b[4];
        #pragma unroll
        for (int mf = 0; mf < 4; ++mf)
            a[mf] = W[(size_t)(mf * 16 + rl) * 32 + c8 + q];
        #pragma unroll
        for (int nf = 0; nf < 4; ++nf)
            b[nf] = X[(size_t)(pix0 + nf * 16 + rl) * 32 + c8 + q];
        #pragma unroll
        for (int mf = 0; mf < 4; ++mf)
            #pragma unroll
            for (int nf = 0; nf < 4; ++nf)
                acc[mf][nf] = __builtin_amdgcn_mfma_f32_16x16x32_bf16(a[mf], b[nf], acc[mf][nf], 0, 0, 0);
    }

    if (type < 2) {
        unsigned short* dst = comb_t + (size_t)s * 4096 * 512 + type * 256;
        #pragma unroll
        for (int mf = 0; mf < 4; ++mf) {
            const int o_loc = wvi * 64 + mf * 16 + q * 4;
            const float4 bz = *(const float4*)(bias + o_loc);
            #pragma unroll
            for (int nf = 0; nf < 4; ++nf) {
                const int pix = pix0 + nf * 16 + rl;
                uint2 pk;
                pk.x = pk_bf16(acc[mf][nf][0] + bz.x, acc[mf][nf][1] + bz.y);
                pk.y = pk_bf16(acc[mf][nf][2] + bz.z, acc[mf][nf][3] + bz.w);
                *(uint2*)(dst + (size_t)pix * 512 + o_loc) = pk;
            }
        }
    } else {
        unsigned char* dst8 = vbuf8 + (size_t)s * 4096 * 256;
        #pragma unroll
        for (int mf = 0; mf < 4; ++mf) {
            const int l = mf * 16 + q * 4;          // local ch within 64-group
            const int p = wvi * 64 + ((l >> 3) & 3) * 16 + (l >> 5) * 8 + (l & 7);
            const float4 bz = *(const float4*)(bias + wvi * 64 + l);
            #pragma unroll
            for (int nf = 0; nf < 4; ++nf) {
                const int pix = pix0 + nf * 16 + rl;
                int u = __builtin_amdgcn_cvt_pk_fp8_f32(acc[mf][nf][0] + bz.x,
                                                        acc[mf][nf][1] + bz.y, 0, false);
                u = __builtin_amdgcn_cvt_pk_fp8_f32(acc[mf][nf][2] + bz.z,
                                                    acc[mf][nf][3] + bz.w, u, true);
                *(unsigned*)(dst8 + (size_t)pix * 256 + p) = (unsigned)u;
            }
        }
    }
}

// ---------------------------------------------------------------------------
// Kernel 2: 3x3 conv 512->108 as implicit GEMM on MFMA bf16 (r10 full-row form).
// ---------------------------------------------------------------------------
__global__ __launch_bounds__(256) void offconv_mfma(
    const unsigned short* __restrict__ comb_t,
    const unsigned short* __restrict__ wT2,
    const float* __restrict__ b_off,
    float* __restrict__ dout, float* __restrict__ mask_ws)
{
    const int bid = blockIdx.x;
    const int s = bid & 7;          // XCD = linear_bid % 8 = s
    const int h = bid >> 3;
    const int t = threadIdx.x;
    const int lane = t & 63;
    const int wid  = t >> 6;
    const int q    = lane >> 4;
    const int rl   = lane & 15;

    __shared__ __align__(16) unsigned short tb[2][792 * 8];

    const short8* cbv = (const short8*)comb_t + (size_t)s * 4096 * 64;
    const short8* wv  = (const short8*)wT2;

    const int i1 = t + 256, i2 = t + 512, i3 = t + 768;

    auto sload = [&](int idx, int c8) -> short8 {
        int x = idx >> 2, cq = idx & 3;
        int ky = x / 66, xx = x - ky * 66;
        int hh = h + ky - 1, gx = xx - 1;
        short8 v = {0, 0, 0, 0, 0, 0, 0, 0};
        if (hh >= 0 && hh < 64 && gx >= 0 && gx < 64)
            v = cbv[(size_t)(hh * 64 + gx) * 64 + c8 + cq];
        return v;
    };
    auto swrite = [&](unsigned short* buf, int idx, short8 v) {
        int x = idx >> 2, cq = idx & 3;
        int qs = cq ^ ((x >> 1) & 3);
        *((short8*)buf + x * 4 + qs) = v;
    };

    f32x4 acc[2][4];
    #pragma unroll
    for (int ma = 0; ma < 2; ++ma)
        #pragma unroll
        for (int nf = 0; nf < 4; ++nf)
            acc[ma][nf] = (f32x4){0.f, 0.f, 0.f, 0.f};

    short8 r0 = sload(t, 0), r1 = sload(i1, 0), r2 = sload(i2, 0);
    short8 r3 = {0,0,0,0,0,0,0,0};
    if (i3 < 792) r3 = sload(i3, 0);
    swrite(tb[0], t, r0); swrite(tb[0], i1, r1); swrite(tb[0], i2, r2);
    if (i3 < 792) swrite(tb[0], i3, r3);
    __syncthreads();

    for (int sl = 0; sl < 16; ++sl) {
        const int c8 = sl * 4;
        if (sl < 15) {
            r0 = sload(t, c8 + 4); r1 = sload(i1, c8 + 4); r2 = sload(i2, c8 + 4);
            if (i3 < 792) r3 = sload(i3, c8 + 4);
        }
        short8 a[2][9];
        #pragma unroll
        for (int ma = 0; ma < 2; ++ma) {
            const int o = (wid * 2 + ma) * 16 + rl;
            #pragma unroll
            for (int kk = 0; kk < 9; ++kk)
                a[ma][kk] = wv[((size_t)(kk * 16 + sl) * 128 + o) * 4 + q];
        }
        const unsigned short* bufc = tb[sl & 1];
        #pragma unroll
        for (int kk = 0; kk < 9; ++kk) {
            const int ky = kk / 3, kx = kk % 3;
            #pragma unroll
            for (int nf = 0; nf < 4; ++nf) {
                const int xr = ky * 66 + nf * 16 + rl + kx;
                short8 b = *((const short8*)bufc + xr * 4 + (q ^ ((xr >> 1) & 3)));
                acc[0][nf] = __builtin_amdgcn_mfma_f32_16x16x32_bf16(a[0][kk], b, acc[0][nf], 0, 0, 0);
                acc[1][nf] = __builtin_amdgcn_mfma_f32_16x16x32_bf16(a[1][kk], b, acc[1][nf], 0, 0, 0);
            }
        }
        if (sl < 15) {
            unsigned short* bufn = tb[(sl + 1) & 1];
            swrite(bufn, t, r0); swrite(bufn, i1, r1); swrite(bufn, i2, r2);
            if (i3 < 792) swrite(bufn, i3, r3);
        }
        __syncthreads();
    }

    const size_t obase = FUSED_SZ + (s < 4 ? 0 : OFF_SZ) + (size_t)(s & 3) * 72 * HW + (size_t)h * 64;
    const size_t mbase = (size_t)s * 36 * HW + (size_t)h * 64;
    #pragma unroll
    for (int ma = 0; ma < 2; ++ma) {
        #pragma unroll
        for (int r = 0; r < 4; ++r) {
            const int o = (wid * 2 + ma) * 16 + q * 4 + r;
            if (o >= 108) continue;
            const float bz = b_off[o];
            #pragma unroll
            for (int nf = 0; nf < 4; ++nf) {
                const int w = nf * 16 + rl;
                float v = acc[ma][nf][r] + bz;
                if (o < 72)
                    dout[obase + (size_t)o * HW + w] = v;
                else
                    mask_ws[mbase + (size_t)(o - 72) * HW + w] = 1.f / (1.f + expf(-v));
            }
        }
    }
}

// ---------------------------------------------------------------------------
// Kernel 3: deformable conv + residual fuse, MFMA bf16, zero LDS / barriers.
// Round 18: named two-phase (E/O) gather pipeline per T15 idiom — NO rotation
// copies, NO conditionally-initialized registers, rolled pair loop.  Each
// tap's 8 gathers get one full blend+MFMA phase in flight before consumption.
// Grid caps waves at 16/CU, so VGPR up to 128 is free.
// ---------------------------------------------------------------------------
__global__ __launch_bounds__(256) void dcn_fuse_mfma(
    const float* __restrict__ rife, const unsigned short* __restrict__ dcnwT,
    const float* __restrict__ gamma,
    const unsigned char* __restrict__ vbuf8, const float* __restrict__ mask_ws,
    float* __restrict__ dout)
{
    const int bid = blockIdx.x;
    const int c   = bid & 15;
    const int h   = bid >> 4;
    const int b   = c >> 2;
    const int g   = c & 3;
    const int t    = threadIdx.x;
    const int wv   = t >> 6;
    const int lane = t & 63;
    const int q    = lane >> 4;
    const int rl   = lane & 15;
    const int pix  = wv * 16 + rl;

    const short8* aT = (const short8*)dcnwT;

    f32x4 acc[4];
    #pragma unroll
    for (int ma = 0; ma < 4; ++ma) acc[ma] = (f32x4){0.f, 0.f, 0.f, 0.f};

    // 32-bit element offsets from uniform bases
    const unsigned obA = (unsigned)(4u * 256u * HW) + (unsigned)((b * 72 + g * 18) * HW + h * 64 + pix);
    const unsigned obB = obA + (unsigned)(4u * 72u * HW);
    const unsigned mbA = (unsigned)((b * 36 + g * 9) * HW + h * 64 + pix);
    const unsigned mbB = mbA + (unsigned)(4u * 36u * HW);
    const unsigned vA  = (unsigned)(b * 4096 * 256 + g * 64 + q * 16);
    const unsigned vB  = vA + 4u * 4096u * 256u;

    auto bil = [&](float py, float px, float mv,
                   float& w00, float& w01, float& w10, float& w11,
                   unsigned& o00, unsigned& o01, unsigned& o10, unsigned& o11) {
        const float y0f = floorf(py), x0f = floorf(px);
        const float fy = py - y0f, fx = px - x0f;
        const int y0 = (int)y0f, x0 = (int)x0f;
        const bool vy0 = (y0 >= 0) && (y0 < 64);
        const bool vy1 = (y0 >= -1) && (y0 < 63);
        const bool vx0 = (x0 >= 0) && (x0 < 64);
        const bool vx1 = (x0 >= -1) && (x0 < 63);
        w00 = (1.f - fy) * (1.f - fx) * mv * (float)(vy0 && vx0);
        w01 = (1.f - fy) * fx        * mv * (float)(vy0 && vx1);
        w10 = fy * (1.f - fx)        * mv * (float)(vy1 && vx0);
        w11 = fy * fx                * mv * (float)(vy1 && vx1);
        const int yc0 = min(max(y0, 0), 63),     yc1 = min(max(y0 + 1, 0), 63);
        const int xc0 = min(max(x0, 0), 63),     xc1 = min(max(x0 + 1, 0), 63);
        o00 = (unsigned)(yc0 * 64 + xc0) * 256u;
        o01 = (unsigned)(yc0 * 64 + xc1) * 256u;
        o10 = (unsigned)(yc1 * 64 + xc0) * 256u;
        o11 = (unsigned)(yc1 * 64 + xc1) * 256u;
    };
    // blend 4 fp8 corner vectors (16 ch each) into two bf16x8 fragments
    auto blend8 = [&](uint4 c00, uint4 c01, uint4 c10, uint4 c11,
                      float w00, float w01, float w10, float w11,
                      short8& bf0, short8& bf1) {
        U8 u0, u1;
        {
            f32x2 eL = w00*CVT8(c00.x,false) + w01*CVT8(c01.x,false) + w10*CVT8(c10.x,false) + w11*CVT8(c11.x,false);
            f32x2 eH = w00*CVT8(c00.x,true)  + w01*CVT8(c01.x,true)  + w10*CVT8(c10.x,true)  + w11*CVT8(c11.x,true);
            u0.u[0] = pk_bf16(eL.x, eL.y); u0.u[1] = pk_bf16(eH.x, eH.y);
        }
        {
            f32x2 eL = w00*CVT8(c00.y,false) + w01*CVT8(c01.y,false) + w10*CVT8(c10.y,false) + w11*CVT8(c11.y,false);
            f32x2 eH = w00*CVT8(c00.y,true)  + w01*CVT8(c01.y,true)  + w10*CVT8(c10.y,true)  + w11*CVT8(c11.y,true);
            u0.u[2] = pk_bf16(eL.x, eL.y); u0.u[3] = pk_bf16(eH.x, eH.y);
        }
        {
            f32x2 eL = w00*CVT8(c00.z,false) + w01*CVT8(c01.z,false) + w10*CVT8(c10.z,false) + w11*CVT8(c11.z,false);
            f32x2 eH = w00*CVT8(c00.z,true)  + w01*CVT8(c01.z,true)  + w10*CVT8(c10.z,true)  + w11*CVT8(c11.z,true);
            u1.u[0] = pk_bf16(eL.x, eL.y); u1.u[1] = pk_bf16(eH.x, eH.y);
        }
        {
            f32x2 eL = w00*CVT8(c00.w,false) + w01*CVT8(c01.w,false) + w10*CVT8(c10.w,false) + w11*CVT8(c11.w,false);
            f32x2 eH = w00*CVT8(c00.w,true)  + w01*CVT8(c01.w,true)  + w10*CVT8(c10.w,true)  + w11*CVT8(c11.w,true);
            u1.u[2] = pk_bf16(eL.x, eL.y); u1.u[3] = pk_bf16(eH.x, eH.y);
        }
        bf0 = u0.s; bf1 = u1.s;
    };

    // --- named pipeline sets (no arrays, no rotation) ---
    float wA00E, wA01E, wA10E, wA11E, wB00E, wB01E, wB10E, wB11E;
    float wA00O, wA01O, wA10O, wA11O, wB00O, wB01O, wB10O, wB11O;
    uint4 A00E, A01E, A10E, A11E, B00E, B01E, B10E, B11E;
    uint4 A00O, A01O, A10O, A11O, B00O, B01O, B10O, B11O;

#define ISSUE(K, S) {                                                          \
    const int ky_ = (K) / 3, kx_ = (K) - ((K) / 3) * 3;                        \
    unsigned o0_, o1_, o2_, o3_;                                               \
    float cy_ = dout[obA + (unsigned)((K) * 2 * HW)];                          \
    float cx_ = dout[obA + (unsigned)(((K) * 2 + 1) * HW)];                    \
    float cm_ = mask_ws[mbA + (unsigned)((K) * HW)];                           \
    bil(cy_ + (float)(h - 1 + ky_), cx_ + (float)(pix - 1 + kx_), cm_,         \
        wA00##S, wA01##S, wA10##S, wA11##S, o0_, o1_, o2_, o3_);               \
    A00##S = *(const uint4*)(vbuf8 + vA + o0_);                                \
    A01##S = *(const uint4*)(vbuf8 + vA + o1_);                                \
    A10##S = *(const uint4*)(vbuf8 + vA + o2_);                                \
    A11##S = *(const uint4*)(vbuf8 + vA + o3_);                                \
    cy_ = dout[obB + (unsigned)((K) * 2 * HW)];                                \
    cx_ = dout[obB + (unsigned)(((K) * 2 + 1) * HW)];                          \
    cm_ = mask_ws[mbB + (unsigned)((K) * HW)];                                 \
    bil(cy_ + (float)(h - 1 + ky_), cx_ + (float)(pix - 1 + kx_), cm_,         \
        wB00##S, wB01##S, wB10##S, wB11##S, o0_, o1_, o2_, o3_);               \
    B00##S = *(const uint4*)(vbuf8 + vB + o0_);                                \
    B01##S = *(const uint4*)(vbuf8 + vB + o1_);                                \
    B10##S = *(const uint4*)(vbuf8 + vB + o2_);                                \
    B11##S = *(const uint4*)(vbuf8 + vB + o3_);                                \
}

#define CONSUME(K, S) {                                                        \
    short8 af00 = aT[((size_t)((K) * 8 + g * 2 + 0) * 64 + 0 * 16 + rl) * 4 + q]; \
    short8 af10 = aT[((size_t)((K) * 8 + g * 2 + 0) * 64 + 1 * 16 + rl) * 4 + q]; \
    short8 af20 = aT[((size_t)((K) * 8 + g * 2 + 0) * 64 + 2 * 16 + rl) * 4 + q]; \
    short8 af30 = aT[((size_t)((K) * 8 + g * 2 + 0) * 64 + 3 * 16 + rl) * 4 + q]; \
    short8 af01 = aT[((size_t)((K) * 8 + g * 2 + 1) * 64 + 0 * 16 + rl) * 4 + q]; \
    short8 af11 = aT[((size_t)((K) * 8 + g * 2 + 1) * 64 + 1 * 16 + rl) * 4 + q]; \
    short8 af21 = aT[((size_t)((K) * 8 + g * 2 + 1) * 64 + 2 * 16 + rl) * 4 + q]; \
    short8 af31 = aT[((size_t)((K) * 8 + g * 2 + 1) * 64 + 3 * 16 + rl) * 4 + q]; \
    short8 bf0_, bf1_;                                                         \
    blend8(A00##S, A01##S, A10##S, A11##S,                                     \
           wA00##S, wA01##S, wA10##S, wA11##S, bf0_, bf1_);                    \
    acc[0] = __builtin_amdgcn_mfma_f32_16x16x32_bf16(af00, bf0_, acc[0], 0, 0, 0); \
    acc[1] = __builtin_amdgcn_mfma_f32_16x16x32_bf16(af10, bf0_, acc[1], 0, 0, 0); \
    acc[2] = __builtin_amdgcn_mfma_f32_16x16x32_bf16(af20, bf0_, acc[2], 0, 0, 0); \
    acc[3] = __builtin_amdgcn_mfma_f32_16x16x32_bf16(af30, bf0_, acc[3], 0, 0, 0); \
    acc[0] = __builtin_amdgcn_mfma_f32_16x16x32_bf16(af01, bf1_, acc[0], 0, 0, 0); \
    acc[1] = __builtin_amdgcn_mfma_f32_16x16x32_bf16(af11, bf1_, acc[1], 0, 0, 0); \
    acc[2] = __builtin_amdgcn_mfma_f32_16x16x32_bf16(af21, bf1_, acc[2], 0, 0, 0); \
    acc[3] = __builtin_amdgcn_mfma_f32_16x16x32_bf16(af31, bf1_, acc[3], 0, 0, 0); \
    blend8(B00##S, B01##S, B10##S, B11##S,                                     \
           wB00##S, wB01##S, wB10##S, wB11##S, bf0_, bf1_);                    \
    acc[0] = __builtin_amdgcn_mfma_f32_16x16x32_bf16(af00, bf0_, acc[0], 0, 0, 0); \
    acc[1] = __builtin_amdgcn_mfma_f32_16x16x32_bf16(af10, bf0_, acc[1], 0, 0, 0); \
    acc[2] = __builtin_amdgcn_mfma_f32_16x16x32_bf16(af20, bf0_, acc[2], 0, 0, 0); \
    acc[3] = __builtin_amdgcn_mfma_f32_16x16x32_bf16(af30, bf0_, acc[3], 0, 0, 0); \
    acc[0] = __builtin_amdgcn_mfma_f32_16x16x32_bf16(af01, bf1_, acc[0], 0, 0, 0); \
    acc[1] = __builtin_amdgcn_mfma_f32_16x16x32_bf16(af11, bf1_, acc[1], 0, 0, 0); \
    acc[2] = __builtin_amdgcn_mfma_f32_16x16x32_bf16(af21, bf1_, acc[2], 0, 0, 0); \
    acc[3] = __builtin_amdgcn_mfma_f32_16x16x32_bf16(af31, bf1_, acc[3], 0, 0, 0); \
}
    // note: dcnwT layout index (k*4+g)*2+ks == k*8 + g*2 + ks

    ISSUE(0, E);
    for (int kp = 0; kp < 4; ++kp) {
        const int k = kp * 2;
        ISSUE(k + 1, O);
        CONSUME(k, E);
        ISSUE(k + 2, E);
        CONSUME(k + 1, O);
    }
    CONSUME(8, E);
#undef ISSUE
#undef CONSUME

    const float gm = gamma[0];
    #pragma unroll
    for (int ma = 0; ma < 4; ++ma) {
        #pragma unroll
        for (int r = 0; r < 4; ++r) {
            const int o = g * 64 + ma * 16 + q * 4 + r;
            const unsigned addr = (unsigned)((b * 256 + o) * HW + h * 64 + pix);
            dout[addr] = rife[addr] + gm * acc[ma][r];
        }
    }
}

// ---------------------------------------------------------------------------
extern "C" void kernel_launch(void* const* d_in, const int* in_sizes, int n_in,
                              void* d_out, int out_size, void* d_ws, size_t ws_size,
                              hipStream_t stream)
{
    const float* rife  = (const float*)d_in[0];
    const float* d0    = (const float*)d_in[1];
    const float* d1    = (const float*)d_in[2];
    const float* wq    = (const float*)d_in[3];
    const float* bq    = (const float*)d_in[4];
    const float* wk    = (const float*)d_in[5];
    const float* bk    = (const float*)d_in[6];
    const float* wv    = (const float*)d_in[7];
    const float* bv    = (const float*)d_in[8];
    const float* w_off = (const float*)d_in[9];
    const float* b_off = (const float*)d_in[10];
    const float* dcnw  = (const float*)d_in[11];
    const float* gamma = (const float*)d_in[12];
    float* out = (float*)d_out;
    char* wsb  = (char*)d_ws;

    // ws layout (bytes)
    unsigned short* comb_t = (unsigned short*)(wsb);              // 33,554,432
    unsigned char*  vbuf8  = (unsigned char*)(wsb + 33554432);    //  8,388,608 (fp8)
    float*          mws    = (float*)(wsb + 50331648);            //  4,718,592
    unsigned short* wT2    = (unsigned short*)(wsb + 55050240);   //  1,179,648
    unsigned short* dcnwT  = (unsigned short*)(wsb + 56229888);   //    294,912
    unsigned short* xT     = (unsigned short*)(wsb + 56524800);   // 25,165,824
    unsigned short* wqkvT  = (unsigned short*)(wsb + 81690624);   //    393,216
    // total: ~82.1 MB

    prep_all<<<3648, 256, 0, stream>>>(w_off, dcnw, wq, wk, wv, wT2, dcnwT, wqkvT);
    xprep<<<dim3(64, 12), 256, 0, stream>>>(rife, d0, d1, xT);
    qkv_mfma<<<dim3(64, 3, 8), 256, 0, stream>>>(xT, wqkvT, bq, bk, bv, comb_t, vbuf8);
    offconv_mfma<<<512, 256, 0, stream>>>(comb_t, wT2, b_off, out, mws);
    dcn_fuse_mfma<<<1024, 256, 0, stream>>>(rife, dcnwT, gamma, vbuf8, mws, out);
}